// Round 1
// baseline (1153.205 us; speedup 1.0000x reference)
//
#include <hip/hip_runtime.h>
#include <hip/hip_bf16.h>

// Fused Linear + CrossEntropy on MI355X.
// Round 3: port K-loop to the verified m201 8-phase discipline:
//  - ds_reads issued BEFORE the leading barrier, lgkmcnt(0)+sched_barrier after
//  - double barrier bracketing each setprio'd 16-MFMA cluster (T5 role-split)
//  - 6-stage-unit-deep prefetch stream (1.5 K-tiles, 12 loads in flight),
//    counted s_waitcnt vmcnt(8) at phases 1 and 3 only.
// Stage stream (unit = 2 global_load_lds per wave), shift S=6:
//   tile k ph0: A1(k+1) -> (nxt,kk1)   [region dead since (k-1,ph3)]
//   tile k ph1: B1(k+1) -> (nxt,kk1)
//   tile k ph2: A0(k+2) -> (cur,kk0)   [region dead after (k,ph1) trailing barrier]
//   tile k ph3: B0(k+2) -> (cur,kk0)
// Waits: ph1/ph3 vmcnt(8) retire the 2 oldest units, protecting the reads
// that occur after the following barrier (ph2 of this tile / ph0 of next).

typedef __attribute__((ext_vector_type(8))) short short8;
typedef __attribute__((ext_vector_type(8))) unsigned short ushort8;
typedef __attribute__((ext_vector_type(4))) float f32x4;

#define BT_TOTAL 8192
#define HDIM     2048
#define VDIM     32000
#define IGNORE_INDEX (-100)

constexpr int BM = 256, BN = 256, BK = 64;
constexpr int NVT = VDIM / BN;      // 125 vocab tiles
constexpr int NMT = BT_TOTAL / BM;  // 32 token tiles
constexpr int NKT = HDIM / BK;      // 32 K-tiles

__device__ __forceinline__ unsigned short f2bf(float f) {
    unsigned u = __float_as_uint(f);
    u = (u + 0x7FFFu + ((u >> 16) & 1u)) >> 16;   // RNE
    return (unsigned short)u;
}

__global__ void cvt_kernel(const float* __restrict__ in, unsigned short* __restrict__ out) {
    size_t i = ((size_t)blockIdx.x * blockDim.x + threadIdx.x) * 8;
    float4 a = *reinterpret_cast<const float4*>(in + i);
    float4 b = *reinterpret_cast<const float4*>(in + i + 4);
    ushort8 r;
    r[0] = f2bf(a.x); r[1] = f2bf(a.y); r[2] = f2bf(a.z); r[3] = f2bf(a.w);
    r[4] = f2bf(b.x); r[5] = f2bf(b.y); r[6] = f2bf(b.z); r[7] = f2bf(b.w);
    *reinterpret_cast<ushort8*>(out + i) = r;
}

#define GLDS(gp, lp) __builtin_amdgcn_global_load_lds( \
    (const __attribute__((address_space(1))) void*)(gp), \
    (__attribute__((address_space(3))) void*)(lp), 16, 0, 0)

__global__ __launch_bounds__(512, 2)
void flce_gemm(const unsigned short* __restrict__ xb,
               const unsigned short* __restrict__ wb,
               const int* __restrict__ labels,
               float* __restrict__ pmax, float* __restrict__ psum,
               float* __restrict__ tgt) {
    // LDS: A halves [buf][kk] 4 x 16KB at 0, B halves at 65536, scomb at 131072.
    // Half-tile layout (swizzled): row r, k-chunk c (8 bf16 = 16B) stored at byte
    //   (r>>1)*128 + (r&1)*64 + ((c ^ ((r>>1)&3))<<4)
    // -> full-wave ds_read_b128 frag fetch touches 64 distinct 16B slots (0-conflict).
    __shared__ __align__(16) char smem[139264];

    const int t    = threadIdx.x;           // 0..511
    const int lane = t & 63;
    const int wid  = t >> 6;                // 8 waves
    const int li   = lane & 15;
    const int lg   = lane >> 4;             // k-chunk 0..3 within 32-k half
    const int wm   = wid >> 2;              // 2 wave-rows   (128 rows each)
    const int wn   = wid & 3;               // 4 wave-cols   (64 cols each)

    // XCD-bijective supertiled mapping: 4000 blocks, 500/XCD.
    int bid = blockIdx.x;
    int xcd = bid & 7;
    int idx = bid >> 3;                     // 0..499
    int p   = idx / 250;
    int r_  = idx % 250;
    int vt  = r_ >> 1;
    int mt  = xcd * 4 + p * 2 + (r_ & 1);
    const int row0 = mt * BM;
    const int col0 = vt * BN;

    // ---- staging lane constants (inverse-swizzled global source, linear LDS dest)
    const int rowLane  = 2 * (t >> 3) + ((t >> 2) & 1);     // 0..127 (issue adds +128)
    const int srcChunk = (t & 3) ^ ((t >> 3) & 3);
    const unsigned short* aG = xb + (size_t)(row0 + rowLane) * HDIM + srcChunk * 8;
    const unsigned short* bG = wb + (size_t)(col0 + rowLane) * HDIM + srcChunk * 8;
    char* ldsA = smem;
    char* ldsB = smem + 65536;

    // ---- fragment-read lane constant
    const int laneFragOff = (li >> 1) * 128 + (li & 1) * 64
                          + ((lg ^ ((li >> 1) & 3)) << 4);

    f32x4 acc[8][4] = {};   // [mr][nr]: rows wm*128+mr*16+lg*4+j, cols wn*64+nr*16+li

    auto stageA = [&](int buf, int kk, int tile) {
        char* d = ldsA + (buf * 2 + kk) * 16384 + wid * 1024;
        const unsigned short* s = aG + tile * 64 + kk * 32;
        GLDS(s, d);
        GLDS(s + (size_t)128 * HDIM, d + 8192);
    };
    auto stageB = [&](int buf, int kk, int tile) {
        char* d = ldsB + (buf * 2 + kk) * 16384 + wid * 1024;
        const unsigned short* s = bG + tile * 64 + kk * 32;
        GLDS(s, d);
        GLDS(s + (size_t)128 * HDIM, d + 8192);
    };

    // ---- prologue: 6 stage-units in flight (A0,B0,A1,B1 of tile0; A0,B0 of tile1)
    stageA(0, 0, 0); stageB(0, 0, 0); stageA(0, 1, 0); stageB(0, 1, 0);
    stageA(1, 0, 1); stageB(1, 0, 1);
    asm volatile("s_waitcnt vmcnt(8)" ::: "memory");   // retire A0(0),B0(0)
    __builtin_amdgcn_s_barrier();

    for (int kt = 0; kt < NKT; ++kt) {
        const int cur = kt & 1, nxt = cur ^ 1;
        const int kt1 = (kt + 1 < NKT) ? kt + 1 : NKT - 1;  // clamped dummy at tail
        const int kt2 = (kt + 2 < NKT) ? kt + 2 : NKT - 1;
        const char* Acur0 = ldsA + (cur * 2 + 0) * 16384 + wm * 8192;
        const char* Acur1 = ldsA + (cur * 2 + 1) * 16384 + wm * 8192;
        const char* Bcur0 = ldsB + (cur * 2 + 0) * 16384 + wn * 4096;
        const char* Bcur1 = ldsB + (cur * 2 + 1) * 16384 + wn * 4096;

        short8 a[4], b0[4];

        // ---- phase 0: MFMA (kk0, m-half0). Stage A1(kt+1).
        #pragma unroll
        for (int i = 0; i < 4; ++i) {
            a[i]  = *(const short8*)(Acur0 + i * 1024 + laneFragOff);
            b0[i] = *(const short8*)(Bcur0 + i * 1024 + laneFragOff);
        }
        stageA(nxt, 1, kt1);
        __builtin_amdgcn_s_barrier();
        asm volatile("s_waitcnt lgkmcnt(0)" ::: "memory");
        __builtin_amdgcn_sched_barrier(0);
        __builtin_amdgcn_s_setprio(1);
        #pragma unroll
        for (int mr = 0; mr < 4; ++mr)
            #pragma unroll
            for (int nr = 0; nr < 4; ++nr)
                acc[mr][nr] = __builtin_amdgcn_mfma_f32_16x16x32_bf16(a[mr], b0[nr], acc[mr][nr], 0, 0, 0);
        __builtin_amdgcn_s_setprio(0);
        __builtin_amdgcn_s_barrier();

        // ---- phase 1: MFMA (kk0, m-half1), reuse b0. Stage B1(kt+1). Wait vmcnt(8).
        #pragma unroll
        for (int i = 0; i < 4; ++i)
            a[i] = *(const short8*)(Acur0 + (4 + i) * 1024 + laneFragOff);
        stageB(nxt, 1, kt1);
        asm volatile("s_waitcnt vmcnt(8)" ::: "memory");   // retire A1(kt),B1(kt)
        __builtin_amdgcn_s_barrier();
        asm volatile("s_waitcnt lgkmcnt(0)" ::: "memory");
        __builtin_amdgcn_sched_barrier(0);
        __builtin_amdgcn_s_setprio(1);
        #pragma unroll
        for (int mr = 0; mr < 4; ++mr)
            #pragma unroll
            for (int nr = 0; nr < 4; ++nr)
                acc[4 + mr][nr] = __builtin_amdgcn_mfma_f32_16x16x32_bf16(a[mr], b0[nr], acc[4 + mr][nr], 0, 0, 0);
        __builtin_amdgcn_s_setprio(0);
        __builtin_amdgcn_s_barrier();

        // ---- phase 2: MFMA (kk1, m-half0). Stage A0(kt+2) into (cur,kk0) [dead].
        #pragma unroll
        for (int i = 0; i < 4; ++i) {
            a[i]  = *(const short8*)(Acur1 + i * 1024 + laneFragOff);
            b0[i] = *(const short8*)(Bcur1 + i * 1024 + laneFragOff);
        }
        stageA(cur, 0, kt2);
        __builtin_amdgcn_s_barrier();
        asm volatile("s_waitcnt lgkmcnt(0)" ::: "memory");
        __builtin_amdgcn_sched_barrier(0);
        __builtin_amdgcn_s_setprio(1);
        #pragma unroll
        for (int mr = 0; mr < 4; ++mr)
            #pragma unroll
            for (int nr = 0; nr < 4; ++nr)
                acc[mr][nr] = __builtin_amdgcn_mfma_f32_16x16x32_bf16(a[mr], b0[nr], acc[mr][nr], 0, 0, 0);
        __builtin_amdgcn_s_setprio(0);
        __builtin_amdgcn_s_barrier();

        // ---- phase 3: MFMA (kk1, m-half1), reuse b0. Stage B0(kt+2). Wait vmcnt(8).
        #pragma unroll
        for (int i = 0; i < 4; ++i)
            a[i] = *(const short8*)(Acur1 + (4 + i) * 1024 + laneFragOff);
        stageB(cur, 0, kt2);
        asm volatile("s_waitcnt vmcnt(8)" ::: "memory");   // retire A0(kt+1),B0(kt+1)
        __builtin_amdgcn_s_barrier();
        asm volatile("s_waitcnt lgkmcnt(0)" ::: "memory");
        __builtin_amdgcn_sched_barrier(0);
        __builtin_amdgcn_s_setprio(1);
        #pragma unroll
        for (int mr = 0; mr < 4; ++mr)
            #pragma unroll
            for (int nr = 0; nr < 4; ++nr)
                acc[4 + mr][nr] = __builtin_amdgcn_mfma_f32_16x16x32_bf16(a[mr], b0[nr], acc[4 + mr][nr], 0, 0, 0);
        __builtin_amdgcn_s_setprio(0);
        __builtin_amdgcn_s_barrier();
    }

    // ---- fused online-softmax epilogue over this 256x256 logits tile ----
    float* scombM = (float*)(smem + 131072);          // [4][256]
    float* scombS = scombM + 1024;                    // [4][256]
    __syncthreads();   // drains dangling prefetches + converges before scomb use

    #pragma unroll
    for (int mr = 0; mr < 8; ++mr) {
        #pragma unroll
        for (int j = 0; j < 4; ++j) {
            float v = fmaxf(fmaxf(acc[mr][0][j], acc[mr][1][j]),
                            fmaxf(acc[mr][2][j], acc[mr][3][j]));
            v = fmaxf(v, __shfl_xor(v, 1));
            v = fmaxf(v, __shfl_xor(v, 2));
            v = fmaxf(v, __shfl_xor(v, 4));
            v = fmaxf(v, __shfl_xor(v, 8));
            float s = __expf(acc[mr][0][j] - v) + __expf(acc[mr][1][j] - v)
                    + __expf(acc[mr][2][j] - v) + __expf(acc[mr][3][j] - v);
            s += __shfl_xor(s, 1);
            s += __shfl_xor(s, 2);
            s += __shfl_xor(s, 4);
            s += __shfl_xor(s, 8);
            int row = wm * 128 + mr * 16 + lg * 4 + j;
            if (li == 0) {
                scombM[wn * 256 + row] = v;
                scombS[wn * 256 + row] = s;
            }
            // target-logit extraction
            int token = row0 + row;
            int lc = labels[token] - col0 - wn * 64;
            if (lc >= 0 && lc < 64 && (lc & 15) == li) {
                int nr = lc >> 4;
                float val = (nr == 0) ? acc[mr][0][j] : (nr == 1) ? acc[mr][1][j]
                          : (nr == 2) ? acc[mr][2][j] : acc[mr][3][j];
                tgt[token] = val;
            }
        }
    }
    __syncthreads();
    if (t < 256) {
        float m = scombM[t], s = scombS[t];
        #pragma unroll
        for (int w = 1; w < 4; ++w) {
            float m2 = scombM[w * 256 + t], s2 = scombS[w * 256 + t];
            float mm = fmaxf(m, m2);
            s = s * __expf(m - mm) + s2 * __expf(m2 - mm);
            m = mm;
        }
        size_t o = (size_t)vt * BT_TOTAL + row0 + t;
        pmax[o] = m;
        psum[o] = s;
    }
}

__global__ void flce_reduce(const float* __restrict__ pmax, const float* __restrict__ psum,
                            const float* __restrict__ tgt, const int* __restrict__ labels,
                            float* __restrict__ accum) {
    int token = blockIdx.x * 256 + threadIdx.x;
    float m = -INFINITY, s = 0.f;
    for (int v = 0; v < NVT; ++v) {
        float pm = pmax[(size_t)v * BT_TOTAL + token];
        float ps = psum[(size_t)v * BT_TOTAL + token];
        float nm = fmaxf(m, pm);
        s = s * __expf(m - nm) + ps * __expf(pm - nm);
        m = nm;
    }
    float nll = 0.f, cnt = 0.f;
    int lab = labels[token];
    if (lab != IGNORE_INDEX) {
        nll = (m + __logf(s)) - tgt[token];
        cnt = 1.f;
    }
    #pragma unroll
    for (int d = 32; d > 0; d >>= 1) {
        nll += __shfl_down(nll, d);
        cnt += __shfl_down(cnt, d);
    }
    __shared__ float sn[4], sc[4];
    int w = threadIdx.x >> 6;
    if ((threadIdx.x & 63) == 0) { sn[w] = nll; sc[w] = cnt; }
    __syncthreads();
    if (threadIdx.x == 0) {
        atomicAdd(&accum[0], sn[0] + sn[1] + sn[2] + sn[3]);
        atomicAdd(&accum[1], sc[0] + sc[1] + sc[2] + sc[3]);
    }
}

__global__ void flce_final(const float* __restrict__ accum, float* __restrict__ out) {
    if (threadIdx.x == 0) out[0] = accum[0] / fmaxf(accum[1], 1.0f);
}

extern "C" void kernel_launch(void* const* d_in, const int* in_sizes, int n_in,
                              void* d_out, int out_size, void* d_ws, size_t ws_size,
                              hipStream_t stream) {
    const float* hs     = (const float*)d_in[0];   // [8192, 2048] fp32
    const int*   labels = (const int*)d_in[1];     // [8192]
    const float* wt     = (const float*)d_in[2];   // [32000, 2048] fp32

    char* ws = (char*)d_ws;
    unsigned short* xb    = (unsigned short*)(ws);                 // 33,554,432 B
    unsigned short* wb    = (unsigned short*)(ws + 33554432);      // 131,072,000 B
    float*          pmax  = (float*)(ws + 164626432);              // 4,096,000 B
    float*          psum  = (float*)(ws + 168722432);              // 4,096,000 B
    float*          tgt   = (float*)(ws + 172818432);              // 32,768 B
    float*          accum = (float*)(ws + 172851200);              // 8 B

    hipMemsetAsync(accum, 0, 8, stream);
    cvt_kernel<<<16777216 / 2048, 256, 0, stream>>>(hs, xb);
    cvt_kernel<<<65536000 / 2048, 256, 0, stream>>>(wt, wb);
    flce_gemm<<<NMT * NVT, 512, 0, stream>>>(xb, wb, labels, pmax, psum, tgt);
    flce_reduce<<<BT_TOTAL / 256, 256, 0, stream>>>(pmax, psum, tgt, labels, accum);
    flce_final<<<1, 64, 0, stream>>>(accum, (float*)d_out);
}